// Round 1
// baseline (273.928 us; speedup 1.0000x reference)
//
#include <hip/hip_runtime.h>

#define CH     64
#define HH     80
#define WW     200
#define HW     16000      // 80*200
#define NPARAM 8513
// param layout (flat per instance): w0[64][66], w1[64][64], w2[64], b0[64], b1[64], b2[1]
#define OFF_W1 4224
#define OFF_W2 8320       // smalls start: w2(64), b0(64), b1(64), b2(1)

#define PX 256            // pixels per block

__global__ __launch_bounds__(256) void condlane_fp32_kernel(
    const float* __restrict__ x,        // [N, 64, 80, 200]
    const float* __restrict__ params,   // [M, 8513]
    float* __restrict__ out,            // [M, 80, 200] flat
    int num_ins)
{
    __shared__ float w0t[66][64];       // transposed: [c][k]
    __shared__ float w1t[64][64];       // transposed: [c][k]
    __shared__ float smalls[193];       // w2[64], b0[64], b1[64], b2[1]
    __shared__ float hbuf[64][PX];      // per-thread h0 column (runtime-c indexable)

    const int tid = threadIdx.x;
    const int m   = blockIdx.y;
    const int n   = m / num_ins;
    const float* pm = params + (size_t)m * NPARAM;

    // stage + transpose weights (coalesced global reads)
    for (int i = tid; i < 4224; i += 256) { int k = i / 66, c = i % 66; w0t[c][k] = pm[i]; }
    for (int i = tid; i < 4096; i += 256) { int k = i >> 6, c = i & 63; w1t[c][k] = pm[OFF_W1 + i]; }
    for (int i = tid; i < 193;  i += 256) smalls[i] = pm[OFF_W2 + i];
    __syncthreads();

    const int p     = blockIdx.x * PX + tid;
    const bool valid = p < HW;
    const int pc    = valid ? p : (HW - 1);          // clamp for safe loads
    const float lx  = (float)(pc % WW) * (1.0f / WW);
    const float ly  = (float)(pc / WW) * (1.0f / WW); // source bug: also /W
    const float* xp = x + (size_t)n * CH * HW + pc;

    // ---- layer 0: 66 -> 64 ----
    float acc[64];
    #pragma unroll
    for (int k = 0; k < 64; ++k)
        acc[k] = smalls[64 + k] + w0t[0][k] * lx + w0t[1][k] * ly;

    for (int c = 0; c < 64; c += 4) {
        const float f0 = xp[(size_t)(c + 0) * HW];
        const float f1 = xp[(size_t)(c + 1) * HW];
        const float f2 = xp[(size_t)(c + 2) * HW];
        const float f3 = xp[(size_t)(c + 3) * HW];
        #pragma unroll
        for (int k = 0; k < 64; ++k) {
            acc[k] += w0t[2 + c][k] * f0 + w0t[3 + c][k] * f1
                    + w0t[4 + c][k] * f2 + w0t[5 + c][k] * f3;
        }
    }

    // relu -> LDS column (each thread touches only its own column: no sync needed)
    #pragma unroll
    for (int k = 0; k < 64; ++k) hbuf[k][tid] = fmaxf(acc[k], 0.0f);

    // ---- layer 1: 64 -> 64 ----
    float acc2[64];
    #pragma unroll
    for (int k = 0; k < 64; ++k) acc2[k] = smalls[128 + k];

    for (int c = 0; c < 64; c += 4) {
        const float f0 = hbuf[c + 0][tid];
        const float f1 = hbuf[c + 1][tid];
        const float f2 = hbuf[c + 2][tid];
        const float f3 = hbuf[c + 3][tid];
        #pragma unroll
        for (int k = 0; k < 64; ++k) {
            acc2[k] += w1t[c + 0][k] * f0 + w1t[c + 1][k] * f1
                     + w1t[c + 2][k] * f2 + w1t[c + 3][k] * f3;
        }
    }

    // ---- layer 2: 64 -> 1 (+ mask bias shift) ----
    float o = smalls[192] - 2.19f;
    #pragma unroll
    for (int k = 0; k < 64; ++k) o += smalls[k] * fmaxf(acc2[k], 0.0f);

    if (valid) out[(size_t)m * HW + p] = o;
}

extern "C" void kernel_launch(void* const* d_in, const int* in_sizes, int n_in,
                              void* d_out, int out_size, void* d_ws, size_t ws_size,
                              hipStream_t stream) {
    const float* x      = (const float*)d_in[0];
    const float* params = (const float*)d_in[1];
    float* out          = (float*)d_out;

    const int N = in_sizes[0] / (CH * HW);          // 4
    const int M = in_sizes[1] / NPARAM;             // 32
    const int num_ins = M / N;                      // 8

    dim3 grid((HW + PX - 1) / PX, M);
    condlane_fp32_kernel<<<grid, 256, 0, stream>>>(x, params, out, num_ins);
}

// Round 2
// 52.443 us; speedup vs baseline: 5.2233x; 5.2233x over previous
//
#include <hip/hip_runtime.h>

typedef __attribute__((ext_vector_type(8))) short  short8;   // 8 x bf16 (MFMA A/B frag)
typedef __attribute__((ext_vector_type(4))) float  f32x4;    // MFMA C/D frag
typedef __attribute__((ext_vector_type(2))) unsigned int uint2_;

#define HW     16000
#define WWID   200
#define NPARAM 8513
#define OFF_W1 4224
#define OFF_SM 8320   // w2[64] @8320, b0[64] @8384, b1[64] @8448, b2 @8512
// sparams LDS layout: b0 @0, b1 @64, w2 @128, wloc @192 (64*2 interleaved), b2 @320

__device__ __forceinline__ unsigned f2bf(float f) {   // RNE fp32 -> bf16
    unsigned u = __builtin_bit_cast(unsigned, f);
    return (u + 0x7FFFu + ((u >> 16) & 1u)) >> 16;
}

// block = 256 threads (4 waves), tile = 128 px (32 px per wave), grid = (125, N)
__global__ __launch_bounds__(256) void condlane_mfma(
    const float* __restrict__ x,        // [N, 64, HW]
    const float* __restrict__ params,   // [M, 8513]
    float* __restrict__ out,            // [M, HW]
    int num_ins)
{
    __shared__ short wstage[16384 / 2 * 2]; // 16 frags x 1KB = 16KB (L0: 0..8KB, L1: 8..16KB)
    __shared__ float sparams[324];
    __shared__ short xh[4][32 * 64];        // per-wave [32 px][64 c] bf16, XOR-swizzled (4KB/wave)

    const int tid  = threadIdx.x;
    const int lane = tid & 63;
    const int wid  = tid >> 6;
    const int n    = blockIdx.y;
    const int pxg0 = blockIdx.x * 128 + wid * 32;   // wave's base pixel (tile fits HW exactly)

    short* xw = &xh[wid][0];

    // ---- stage x tile: per-wave own region, [px][c] bf16, swizzled ----
    {
        const int pxl = lane & 31;              // 32 px per wave
        const int chalf = (lane >> 5) * 32;     // lanes 0-31: c 0..31, lanes 32-63: c 32..63
        const float* xp = x + (size_t)n * 64 * HW + (pxg0 + pxl);
        #pragma unroll
        for (int c = 0; c < 32; c += 2) {
            const int cc = chalf + c;
            float f0 = xp[(size_t)cc * HW];
            float f1 = xp[(size_t)(cc + 1) * HW];
            unsigned pk = f2bf(f0) | (f2bf(f1) << 16);
            int byte = pxl * 128 + cc * 2;
            byte ^= (pxl & 7) << 4;
            *(unsigned*)((char*)xw + byte) = pk;
        }
    }
    // no barrier needed: each wave stages and consumes only its own region

    // ---- hoist x B-frags to registers: [ps][ch] ----
    short8 xfrag[2][2];
    #pragma unroll
    for (int ps = 0; ps < 2; ++ps)
        #pragma unroll
        for (int ch = 0; ch < 2; ++ch) {
            int pxl = ps * 16 + (lane & 15);
            int byte = pxl * 128 + ((lane >> 4) * 8 + ch * 32) * 2;
            byte ^= (pxl & 7) << 4;
            xfrag[ps][ch] = *(const short8*)((const char*)xw + byte);
        }

    // location channels (fp32, handled in accumulator init)
    float lxv[2], lyv[2];
    #pragma unroll
    for (int ps = 0; ps < 2; ++ps) {
        int pxg = pxg0 + ps * 16 + (lane & 15);
        lxv[ps] = (float)(pxg % WWID) * (1.0f / WWID);
        lyv[ps] = (float)(pxg / WWID) * (1.0f / WWID);  // source bug: also /W
    }

    for (int mi = 0; mi < num_ins; ++mi) {
        const float* pm = params + (size_t)(n * num_ins + mi) * NPARAM;
        __syncthreads();   // previous iteration's wstage/sparams reads complete

        // ---- stage weights into MFMA-fragment order (bf16), cooperative ----
        #pragma unroll
        for (int it = 0; it < 8; ++it) {       // w0: 2048 dwords
            int idx2 = it * 256 + tid;
            int frag = idx2 >> 8;              // kb*2 + ch
            int l    = (idx2 >> 2) & 63;
            int i2   = (idx2 & 3) * 2;
            int kb = frag >> 1, ch = frag & 1;
            int k = kb * 16 + (l & 15);
            int c = 2 + ch * 32 + (l >> 4) * 8 + i2;   // skip 2 location channels
            const float* src = pm + k * 66 + c;
            unsigned pk = f2bf(src[0]) | (f2bf(src[1]) << 16);
            *(unsigned*)((char*)wstage + idx2 * 4) = pk;
        }
        #pragma unroll
        for (int it = 0; it < 8; ++it) {       // w1: 2048 dwords
            int idx2 = it * 256 + tid;
            int frag = idx2 >> 8;
            int l    = (idx2 >> 2) & 63;
            int i2   = (idx2 & 3) * 2;
            int kb = frag >> 1, ch = frag & 1;
            int k = kb * 16 + (l & 15);
            int c = ch * 32 + (l >> 4) * 8 + i2;
            const float* src = pm + OFF_W1 + k * 64 + c;
            unsigned pk = f2bf(src[0]) | (f2bf(src[1]) << 16);
            *(unsigned*)((char*)wstage + 8192 + idx2 * 4) = pk;
        }
        for (int idx = tid; idx < 321; idx += 256) {   // small params, fp32
            float v;
            if      (idx < 64)  v = pm[OFF_SM + 64 + idx];          // b0
            else if (idx < 128) v = pm[OFF_SM + 128 + (idx - 64)];  // b1
            else if (idx < 192) v = pm[OFF_SM + (idx - 128)];       // w2
            else if (idx < 320) { int k = (idx - 192) >> 1; v = pm[k * 66 + ((idx - 192) & 1)]; } // wloc
            else                v = pm[OFF_SM + 192];               // b2
            sparams[idx] = v;
        }
        __syncthreads();

        // ---- load weight A-frags to registers ----
        short8 w0f[4][2], w1f[4][2];
        #pragma unroll
        for (int kb = 0; kb < 4; ++kb)
            #pragma unroll
            for (int ch = 0; ch < 2; ++ch) {
                w0f[kb][ch] = *(const short8*)((const char*)wstage + ((kb * 2 + ch) * 64 + lane) * 16);
                w1f[kb][ch] = *(const short8*)((const char*)wstage + 8192 + ((kb * 2 + ch) * 64 + lane) * 16);
            }

        float vout[2];
        #pragma unroll
        for (int ps = 0; ps < 2; ++ps) {
            const int g = (lane >> 4) & 3;
            // ---- layer 0: init with bias + fp32 location terms, MFMA over 64 x-channels ----
            f32x4 acc0[4];
            #pragma unroll
            for (int kb = 0; kb < 4; ++kb)
                #pragma unroll
                for (int j = 0; j < 4; ++j) {
                    int k = kb * 16 + g * 4 + j;
                    acc0[kb][j] = sparams[k] + sparams[192 + 2 * k] * lxv[ps]
                                             + sparams[193 + 2 * k] * lyv[ps];
                }
            #pragma unroll
            for (int kb = 0; kb < 4; ++kb) {
                acc0[kb] = __builtin_amdgcn_mfma_f32_16x16x32_bf16(w0f[kb][0], xfrag[ps][0], acc0[kb], 0, 0, 0);
                acc0[kb] = __builtin_amdgcn_mfma_f32_16x16x32_bf16(w0f[kb][1], xfrag[ps][1], acc0[kb], 0, 0, 0);
            }
            // ---- relu -> bf16 h0 back to (reused) per-wave LDS, C-layout write ----
            #pragma unroll
            for (int kb = 0; kb < 4; ++kb) {
                unsigned lo = f2bf(fmaxf(acc0[kb][0], 0.f)) | (f2bf(fmaxf(acc0[kb][1], 0.f)) << 16);
                unsigned hi = f2bf(fmaxf(acc0[kb][2], 0.f)) | (f2bf(fmaxf(acc0[kb][3], 0.f)) << 16);
                int pxl = ps * 16 + (lane & 15);
                int byte = pxl * 128 + (kb * 16 + g * 4) * 2;
                byte ^= (pxl & 7) << 4;
                uint2_ pk; pk.x = lo; pk.y = hi;
                *(uint2_*)((char*)xw + byte) = pk;
            }
            // ---- layer 1 ----
            f32x4 acc1[4];
            #pragma unroll
            for (int kb = 0; kb < 4; ++kb)
                #pragma unroll
                for (int j = 0; j < 4; ++j)
                    acc1[kb][j] = sparams[64 + kb * 16 + g * 4 + j];
            #pragma unroll
            for (int ch = 0; ch < 2; ++ch) {
                int pxl = ps * 16 + (lane & 15);
                int byte = pxl * 128 + ((lane >> 4) * 8 + ch * 32) * 2;
                byte ^= (pxl & 7) << 4;
                short8 hf = *(const short8*)((const char*)xw + byte);
                #pragma unroll
                for (int kb = 0; kb < 4; ++kb)
                    acc1[kb] = __builtin_amdgcn_mfma_f32_16x16x32_bf16(w1f[kb][ch], hf, acc1[kb], 0, 0, 0);
            }
            // ---- layer 2: 64 -> 1 in fp32 VALU (no bf16 rounding of h1) ----
            float v = 0.f;
            #pragma unroll
            for (int kb = 0; kb < 4; ++kb)
                #pragma unroll
                for (int j = 0; j < 4; ++j)
                    v += sparams[128 + kb * 16 + g * 4 + j] * fmaxf(acc1[kb][j], 0.f);
            vout[ps] = v;
        }

        // ---- cross-lane reduce (4 groups of 16 k each) + store ----
        const float b2v = sparams[320] - 2.19f;
        #pragma unroll
        for (int ps = 0; ps < 2; ++ps) {
            float v = vout[ps];
            v += __shfl_xor(v, 16);
            v += __shfl_xor(v, 32);
            if ((lane >> 4) == 0) {
                int pxg = pxg0 + ps * 16 + lane;
                out[(size_t)(n * num_ins + mi) * HW + pxg] = v + b2v;
            }
        }
    }
}

extern "C" void kernel_launch(void* const* d_in, const int* in_sizes, int n_in,
                              void* d_out, int out_size, void* d_ws, size_t ws_size,
                              hipStream_t stream) {
    const float* x      = (const float*)d_in[0];
    const float* params = (const float*)d_in[1];
    float* out          = (float*)d_out;

    const int N = in_sizes[0] / (64 * HW);   // 4
    const int M = in_sizes[1] / NPARAM;      // 32
    const int num_ins = M / N;               // 8

    dim3 grid(HW / 128, N);                  // 125 x 4 = 500 blocks
    condlane_mfma<<<grid, 256, 0, stream>>>(x, params, out, num_ins);
}

// Round 4
// 27.558 us; speedup vs baseline: 9.9402x; 1.9030x over previous
//
#include <hip/hip_runtime.h>

typedef __attribute__((ext_vector_type(8))) short    short8;   // 8 x bf16 (MFMA A/B frag)
typedef __attribute__((ext_vector_type(4))) float    f32x4;    // MFMA C/D frag
typedef __attribute__((ext_vector_type(4))) unsigned uint4_;
typedef __attribute__((ext_vector_type(2))) unsigned uint2_;

#define HW     16000
#define WWID   200
#define NPARAM 8513
// raw param offsets: w0[64][66] @0, w1[64][64] @4224, w2 @8320, b0 @8384, b1 @8448, b2 @8512
// packed ws layout per instance (dwords, stride 6144 = 24KB):
//   w0 frags  [0, 3072)   : 12 frags (ch 0..2 x kb 0..3), frag = ch*4+kb, 256 dwords each
//   w1 frags  [3072, 5120):  8 frags (ch 0..1 x kb 0..3)
//   b1 fp32   [5120, 5184), w2 fp32 [5184, 5248), b2 @5248
#define PACK_STRIDE 6144

__device__ __forceinline__ unsigned f2bf(float f) {   // RNE fp32 -> bf16
    unsigned u = __builtin_bit_cast(unsigned, f);
    return (u + 0x7FFFu + ((u >> 16) & 1u)) >> 16;
}
__device__ __forceinline__ unsigned pkbf2(float a, float b) {
    return f2bf(a) | (f2bf(b) << 16);
}

// layer-0 K-channel mapping: 0..63 -> x[c] (w0 col c+2); 64 -> lx (col 0); 65 -> ly (col 1);
// 66 -> bias (b0[k], paired with constant-1 input channel); 67..95 -> 0
__device__ __forceinline__ float w0val(const float* pm, int k, int c) {
    if (c < 64)  return pm[k * 66 + c + 2];
    if (c == 64) return pm[k * 66 + 0];
    if (c == 65) return pm[k * 66 + 1];
    if (c == 66) return pm[8384 + k];
    return 0.0f;
}

__global__ __launch_bounds__(256) void pack_weights(
    const float* __restrict__ params, unsigned* __restrict__ wp)
{
    const int m   = blockIdx.x;
    const int tid = threadIdx.x;
    const float* pm = params + (size_t)m * NPARAM;
    unsigned* dst = wp + (size_t)m * PACK_STRIDE;

    const int l  = tid >> 2;            // lane 0..63
    const int i0 = (tid & 3) * 2;       // element pair within frag row
    #pragma unroll
    for (int frag = 0; frag < 12; ++frag) {            // w0, K=96
        int ch = frag >> 2, kb = frag & 3;
        int k = kb * 16 + (l & 15);
        int c = ch * 32 + (l >> 4) * 8 + i0;
        dst[frag * 256 + tid] = pkbf2(w0val(pm, k, c), w0val(pm, k, c + 1));
    }
    #pragma unroll
    for (int frag = 0; frag < 8; ++frag) {             // w1, K=64
        int ch = frag >> 2, kb = frag & 3;
        int k = kb * 16 + (l & 15);
        int c = ch * 32 + (l >> 4) * 8 + i0;
        const float* s = pm + 4224 + k * 64 + c;
        dst[3072 + frag * 256 + tid] = pkbf2(s[0], s[1]);
    }
    float* fd = (float*)dst;
    if (tid < 64) {
        fd[5120 + tid] = pm[8448 + tid];   // b1
        fd[5184 + tid] = pm[8320 + tid];   // w2
    }
    if (tid == 0) fd[5248] = pm[8512];     // b2
}

// block = 512 threads (8 waves), wave wid owns instance m = n*num_ins + wid.
// LDS: xt [256 px][128 ch] bf16 (64KB, XOR-swizzled) + per-wave h0 [16 px][64 ch] (2KB each)
__global__ __launch_bounds__(512) void condlane_mfma2(
    const float* __restrict__ x,        // [N, 64, HW]
    const unsigned* __restrict__ wp,    // packed weights
    float* __restrict__ out,            // [M, HW]
    int num_ins)
{
    extern __shared__ char lds[];
    char* xt = lds;                     // 65536 B
    const int tid  = threadIdx.x;
    const int lane = tid & 63;
    const int wid  = tid >> 6;
    const int n    = blockIdx.y;
    const int pxg0 = blockIdx.x * 256;
    char* h0 = lds + 65536 + wid * 2048;

    // ---- stage x tile: [px][ch] bf16, swizzle byte ^= (px&15)<<4 ----
    {
        const int p   = tid & 255;
        const int sel = tid >> 8;
        const int pc  = min(pxg0 + p, HW - 1);
        const float* xp = x + (size_t)n * 64 * HW + pc;
        #pragma unroll
        for (int it = 0; it < 4; ++it) {
            int c0 = sel * 32 + it * 8;
            uint4_ d;
            d.x = pkbf2(xp[(size_t)(c0 + 0) * HW], xp[(size_t)(c0 + 1) * HW]);
            d.y = pkbf2(xp[(size_t)(c0 + 2) * HW], xp[(size_t)(c0 + 3) * HW]);
            d.z = pkbf2(xp[(size_t)(c0 + 4) * HW], xp[(size_t)(c0 + 5) * HW]);
            d.w = pkbf2(xp[(size_t)(c0 + 6) * HW], xp[(size_t)(c0 + 7) * HW]);
            int byte = (p * 256 + c0 * 2) ^ ((p & 15) << 4);
            *(uint4_*)(xt + byte) = d;
        }
        // constant channels 64..95: {lx, ly, 1, 0, 0, ...}
        const int pg = pxg0 + p;   // (values for pg>=HW are never consumed)
        float lx = (float)(pg % WWID) * (1.0f / WWID);
        float ly = (float)(pg / WWID) * (1.0f / WWID);   // source bug: also /W
        uint4_ z; z.x = 0; z.y = 0; z.z = 0; z.w = 0;
        uint4_ cv; cv.x = pkbf2(lx, ly); cv.y = pkbf2(1.0f, 0.0f); cv.z = 0; cv.w = 0;
        int ba = (p * 256 + 128 + sel * 32) ^ ((p & 15) << 4);
        int bb = (p * 256 + 144 + sel * 32) ^ ((p & 15) << 4);
        *(uint4_*)(xt + ba) = (sel == 0) ? cv : z;
        *(uint4_*)(xt + bb) = z;
    }
    __syncthreads();   // the only barrier

    if (wid >= num_ins) return;
    const int m = n * num_ins + wid;
    const unsigned* wm = wp + (size_t)m * PACK_STRIDE;
    const int g  = (lane >> 4) & 3;
    const int hi = lane >> 4;

    // ---- wave-resident weights ----
    short8 w0f[3][4], w1f[2][4];
    #pragma unroll
    for (int ch = 0; ch < 3; ++ch)
        #pragma unroll
        for (int kb = 0; kb < 4; ++kb)
            w0f[ch][kb] = *(const short8*)(wm + (ch * 4 + kb) * 256 + lane * 4);
    #pragma unroll
    for (int ch = 0; ch < 2; ++ch)
        #pragma unroll
        for (int kb = 0; kb < 4; ++kb)
            w1f[ch][kb] = *(const short8*)(wm + 3072 + (ch * 4 + kb) * 256 + lane * 4);
    const float* sm = (const float*)wm;
    f32x4 bias1[4], w2v[4];
    #pragma unroll
    for (int kb = 0; kb < 4; ++kb) {
        bias1[kb] = *(const f32x4*)(sm + 5120 + kb * 16 + g * 4);
        w2v[kb]   = *(const f32x4*)(sm + 5184 + kb * 16 + g * 4);
    }
    const float b2 = sm[5248] - 2.19f;

    const int nsl = min(16, (HW - pxg0) >> 4);
    const int hpx = lane & 15;

    for (int s = 0; s < nsl; ++s) {
        const int pxl = s * 16 + (lane & 15);
        // x B-frags (K=96)
        short8 xf[3];
        #pragma unroll
        for (int ch = 0; ch < 3; ++ch) {
            int byte = (pxl * 256 + ch * 64 + hi * 16) ^ ((pxl & 15) << 4);
            xf[ch] = *(const short8*)(xt + byte);
        }
        // layer 0: acc = 0 (loc + bias folded into K)
        f32x4 acc0[4];
        #pragma unroll
        for (int kb = 0; kb < 4; ++kb) { acc0[kb][0] = 0.f; acc0[kb][1] = 0.f; acc0[kb][2] = 0.f; acc0[kb][3] = 0.f; }
        #pragma unroll
        for (int ch = 0; ch < 3; ++ch)
            #pragma unroll
            for (int kb = 0; kb < 4; ++kb)
                acc0[kb] = __builtin_amdgcn_mfma_f32_16x16x32_bf16(w0f[ch][kb], xf[ch], acc0[kb], 0, 0, 0);
        // relu -> bf16 h0 (per-wave private LDS, swizzle byte ^= (px&7)<<4)
        #pragma unroll
        for (int kb = 0; kb < 4; ++kb) {
            uint2_ pk;
            pk.x = pkbf2(fmaxf(acc0[kb][0], 0.f), fmaxf(acc0[kb][1], 0.f));
            pk.y = pkbf2(fmaxf(acc0[kb][2], 0.f), fmaxf(acc0[kb][3], 0.f));
            int byte = (hpx * 128 + kb * 32 + g * 8) ^ ((hpx & 7) << 4);
            *(uint2_*)(h0 + byte) = pk;
        }
        // layer 1
        short8 hf[2];
        #pragma unroll
        for (int ch = 0; ch < 2; ++ch) {
            int byte = (hpx * 128 + ch * 64 + hi * 16) ^ ((hpx & 7) << 4);
            hf[ch] = *(const short8*)(h0 + byte);
        }
        f32x4 acc1[4];
        #pragma unroll
        for (int kb = 0; kb < 4; ++kb) acc1[kb] = bias1[kb];
        #pragma unroll
        for (int ch = 0; ch < 2; ++ch)
            #pragma unroll
            for (int kb = 0; kb < 4; ++kb)
                acc1[kb] = __builtin_amdgcn_mfma_f32_16x16x32_bf16(w1f[ch][kb], hf[ch], acc1[kb], 0, 0, 0);
        // layer 2: 64 -> 1 in fp32 VALU + cross-group reduce
        float v = 0.f;
        #pragma unroll
        for (int kb = 0; kb < 4; ++kb)
            #pragma unroll
            for (int j = 0; j < 4; ++j)
                v += w2v[kb][j] * fmaxf(acc1[kb][j], 0.f);
        v += __shfl_xor(v, 16);
        v += __shfl_xor(v, 32);
        if (lane < 16)
            out[(size_t)m * HW + pxg0 + s * 16 + lane] = v + b2;
    }
}

extern "C" void kernel_launch(void* const* d_in, const int* in_sizes, int n_in,
                              void* d_out, int out_size, void* d_ws, size_t ws_size,
                              hipStream_t stream) {
    const float* x      = (const float*)d_in[0];
    const float* params = (const float*)d_in[1];
    float* out          = (float*)d_out;

    const int N = in_sizes[0] / (64 * HW);   // 4
    const int M = in_sizes[1] / NPARAM;      // 32
    const int num_ins = M / N;               // 8

    pack_weights<<<M, 256, 0, stream>>>(params, (unsigned*)d_ws);

    dim3 grid((HW + 255) / 256, N);          // 63 x 4 = 252 blocks
    condlane_mfma2<<<grid, 512, 81920, stream>>>(x, (const unsigned*)d_ws, out, num_ins);
}

// Round 5
// 26.302 us; speedup vs baseline: 10.4149x; 1.0478x over previous
//
#include <hip/hip_runtime.h>

typedef __attribute__((ext_vector_type(8))) short    short8;   // 8 x bf16 (MFMA A/B frag)
typedef __attribute__((ext_vector_type(4))) float    f32x4;    // MFMA C/D frag
typedef __attribute__((ext_vector_type(4))) unsigned uint4_;
typedef __attribute__((ext_vector_type(2))) unsigned uint2_;

#define HW     16000
#define WWID   200
#define NPARAM 8513
// raw param offsets: w0[64][66] @0, w1[64][64] @4224, w2 @8320, b0 @8384, b1 @8448, b2 @8512

__device__ __forceinline__ unsigned f2bf(float f) {   // RNE fp32 -> bf16
    unsigned u = __builtin_bit_cast(unsigned, f);
    return (u + 0x7FFFu + ((u >> 16) & 1u)) >> 16;
}
__device__ __forceinline__ unsigned pkbf2(float a, float b) {
    return f2bf(a) | (f2bf(b) << 16);
}
__device__ __forceinline__ short8 mk8(unsigned a, unsigned b, unsigned c, unsigned d) {
    uint4_ u; u.x = a; u.y = b; u.z = c; u.w = d;
    return __builtin_bit_cast(short8, u);
}

// Single fused kernel. block = 512 threads (8 waves); wave wid owns instance
// m = n*num_ins + wid. Weights gathered per-wave from raw params into registers
// (no pack kernel, no workspace). LDS: xt [256 px][128 ch] bf16 XOR-swizzled
// (64KB) + per-wave dual h0 buffers (2 x 2KB each) = 96KB total.
__global__ __launch_bounds__(512, 1) void condlane_fused(
    const float* __restrict__ x,        // [N, 64, HW]
    const float* __restrict__ params,   // [M, 8513]
    float* __restrict__ out,            // [M, HW]
    int num_ins)
{
    extern __shared__ char lds[];
    char* xt = lds;                     // 65536 B
    const int tid  = threadIdx.x;
    const int lane = tid & 63;
    const int wid  = tid >> 6;
    const int n    = blockIdx.y;
    const int pxg0 = blockIdx.x * 256;
    char* h0a = lds + 65536 + wid * 4096;
    char* h0b = h0a + 2048;

    // ---- stage x tile: [px][ch] bf16, swizzle byte ^= (px&15)<<4 ----
    {
        const int p   = tid & 255;
        const int sel = tid >> 8;
        const int pc  = min(pxg0 + p, HW - 1);
        const float* xp = x + (size_t)n * 64 * HW + pc;
        #pragma unroll
        for (int it = 0; it < 4; ++it) {
            int c0 = sel * 32 + it * 8;
            uint4_ d;
            d.x = pkbf2(xp[(size_t)(c0 + 0) * HW], xp[(size_t)(c0 + 1) * HW]);
            d.y = pkbf2(xp[(size_t)(c0 + 2) * HW], xp[(size_t)(c0 + 3) * HW]);
            d.z = pkbf2(xp[(size_t)(c0 + 4) * HW], xp[(size_t)(c0 + 5) * HW]);
            d.w = pkbf2(xp[(size_t)(c0 + 6) * HW], xp[(size_t)(c0 + 7) * HW]);
            int byte = (p * 256 + c0 * 2) ^ ((p & 15) << 4);
            *(uint4_*)(xt + byte) = d;
        }
        // constant channels 64..95: {lx, ly, 1, 0, ...}
        const int pg = pxg0 + p;          // values for pg>=HW never consumed
        float lx = (float)(pg % WWID) * (1.0f / WWID);
        float ly = (float)(pg / WWID) * (1.0f / WWID);   // source bug: also /W
        uint4_ z; z.x = 0; z.y = 0; z.z = 0; z.w = 0;
        uint4_ cv; cv.x = pkbf2(lx, ly); cv.y = pkbf2(1.0f, 0.0f); cv.z = 0; cv.w = 0;
        int ba = (p * 256 + 128 + sel * 32) ^ ((p & 15) << 4);
        int bb = (p * 256 + 144 + sel * 32) ^ ((p & 15) << 4);
        *(uint4_*)(xt + ba) = (sel == 0) ? cv : z;
        *(uint4_*)(xt + bb) = z;
    }

    // ---- per-wave weight gather: raw params -> MFMA fragments in registers ----
    const int m  = n * num_ins + wid;          // wid < num_ins always (8 waves)
    const int g  = (lane >> 4) & 3;
    const int hi = lane >> 4;
    const float* pm = params + (size_t)m * NPARAM;

    short8 w0f[3][4], w1f[2][4];
    #pragma unroll
    for (int kb = 0; kb < 4; ++kb) {
        const int k = kb * 16 + (lane & 15);
        #pragma unroll
        for (int ch = 0; ch < 2; ++ch) {       // w0 x-channels (raw cols 2..65)
            const float* s = pm + k * 66 + 2 + ch * 32 + hi * 8;
            w0f[ch][kb] = mk8(pkbf2(s[0], s[1]), pkbf2(s[2], s[3]),
                              pkbf2(s[4], s[5]), pkbf2(s[6], s[7]));
        }
        // ch 2: K-channels 64..95 = {lx, ly, 1, 0...} -> cols {w00, w01, b0, 0...}
        {
            float a = (hi == 0) ? pm[k * 66 + 0] : 0.0f;
            float b = (hi == 0) ? pm[k * 66 + 1] : 0.0f;
            float c = (hi == 0) ? pm[8384 + k]   : 0.0f;
            w0f[2][kb] = mk8(pkbf2(a, b), pkbf2(c, 0.0f), 0u, 0u);
        }
        #pragma unroll
        for (int ch = 0; ch < 2; ++ch) {       // w1
            const float* s = pm + 4224 + k * 64 + ch * 32 + hi * 8;
            w1f[ch][kb] = mk8(pkbf2(s[0], s[1]), pkbf2(s[2], s[3]),
                              pkbf2(s[4], s[5]), pkbf2(s[6], s[7]));
        }
    }
    f32x4 bias1[4], w2v[4];
    #pragma unroll
    for (int kb = 0; kb < 4; ++kb)
        #pragma unroll
        for (int j = 0; j < 4; ++j) {
            bias1[kb][j] = pm[8448 + kb * 16 + g * 4 + j];
            w2v[kb][j]   = pm[8320 + kb * 16 + g * 4 + j];
        }
    const float b2 = pm[8512] - 2.19f;

    __syncthreads();   // xt ready (the only barrier)

    const int nsl = min(16, (HW - pxg0) >> 4);
    const int hpx = lane & 15;
    const int swz = (lane & 15) << 4;          // pxl&15 == lane&15 for all slices

    for (int sA = 0; sA < 8; ++sA) {
        const int sB = sA + 8;
        const int pxlA = sA * 16 + hpx;
        const int pxlB = pxlA + 128;
        // ---- x B-frags, both slices ----
        short8 xfA[3], xfB[3];
        #pragma unroll
        for (int ch = 0; ch < 3; ++ch) {
            xfA[ch] = *(const short8*)(xt + ((pxlA * 256 + ch * 64 + hi * 16) ^ swz));
            xfB[ch] = *(const short8*)(xt + ((pxlB * 256 + ch * 64 + hi * 16) ^ swz));
        }
        // ---- layer 0 (dual independent chains) ----
        f32x4 acc0A[4], acc0B[4];
        #pragma unroll
        for (int kb = 0; kb < 4; ++kb)
            #pragma unroll
            for (int j = 0; j < 4; ++j) { acc0A[kb][j] = 0.f; acc0B[kb][j] = 0.f; }
        #pragma unroll
        for (int ch = 0; ch < 3; ++ch)
            #pragma unroll
            for (int kb = 0; kb < 4; ++kb) {
                acc0A[kb] = __builtin_amdgcn_mfma_f32_16x16x32_bf16(w0f[ch][kb], xfA[ch], acc0A[kb], 0, 0, 0);
                acc0B[kb] = __builtin_amdgcn_mfma_f32_16x16x32_bf16(w0f[ch][kb], xfB[ch], acc0B[kb], 0, 0, 0);
            }
        // ---- relu -> bf16 h0 (per-wave private LDS, swizzle (px&7)<<4) ----
        #pragma unroll
        for (int kb = 0; kb < 4; ++kb) {
            uint2_ pkA, pkB;
            pkA.x = pkbf2(fmaxf(acc0A[kb][0], 0.f), fmaxf(acc0A[kb][1], 0.f));
            pkA.y = pkbf2(fmaxf(acc0A[kb][2], 0.f), fmaxf(acc0A[kb][3], 0.f));
            pkB.x = pkbf2(fmaxf(acc0B[kb][0], 0.f), fmaxf(acc0B[kb][1], 0.f));
            pkB.y = pkbf2(fmaxf(acc0B[kb][2], 0.f), fmaxf(acc0B[kb][3], 0.f));
            int byte = (hpx * 128 + kb * 32 + g * 8) ^ ((hpx & 7) << 4);
            *(uint2_*)(h0a + byte) = pkA;
            *(uint2_*)(h0b + byte) = pkB;
        }
        // ---- layer 1 ----
        short8 hfA[2], hfB[2];
        #pragma unroll
        for (int ch = 0; ch < 2; ++ch) {
            int byte = (hpx * 128 + ch * 64 + hi * 16) ^ ((hpx & 7) << 4);
            hfA[ch] = *(const short8*)(h0a + byte);
            hfB[ch] = *(const short8*)(h0b + byte);
        }
        f32x4 acc1A[4], acc1B[4];
        #pragma unroll
        for (int kb = 0; kb < 4; ++kb) { acc1A[kb] = bias1[kb]; acc1B[kb] = bias1[kb]; }
        #pragma unroll
        for (int ch = 0; ch < 2; ++ch)
            #pragma unroll
            for (int kb = 0; kb < 4; ++kb) {
                acc1A[kb] = __builtin_amdgcn_mfma_f32_16x16x32_bf16(w1f[ch][kb], hfA[ch], acc1A[kb], 0, 0, 0);
                acc1B[kb] = __builtin_amdgcn_mfma_f32_16x16x32_bf16(w1f[ch][kb], hfB[ch], acc1B[kb], 0, 0, 0);
            }
        // ---- layer 2: 64 -> 1 fp32 VALU + cross-group reduce ----
        float vA = 0.f, vB = 0.f;
        #pragma unroll
        for (int kb = 0; kb < 4; ++kb)
            #pragma unroll
            for (int j = 0; j < 4; ++j) {
                vA += w2v[kb][j] * fmaxf(acc1A[kb][j], 0.f);
                vB += w2v[kb][j] * fmaxf(acc1B[kb][j], 0.f);
            }
        vA += __shfl_xor(vA, 16); vA += __shfl_xor(vA, 32);
        vB += __shfl_xor(vB, 16); vB += __shfl_xor(vB, 32);
        if (lane < 16)
            out[(size_t)m * HW + pxg0 + sA * 16 + lane] = vA + b2;
        else if (lane < 32 && sB < nsl)
            out[(size_t)m * HW + pxg0 + sB * 16 + (lane - 16)] = vB + b2;
    }
}

extern "C" void kernel_launch(void* const* d_in, const int* in_sizes, int n_in,
                              void* d_out, int out_size, void* d_ws, size_t ws_size,
                              hipStream_t stream) {
    const float* x      = (const float*)d_in[0];
    const float* params = (const float*)d_in[1];
    float* out          = (float*)d_out;

    const int N = in_sizes[0] / (64 * HW);   // 4
    const int M = in_sizes[1] / NPARAM;      // 32
    const int num_ins = M / N;               // 8

    dim3 grid((HW + 255) / 256, N);          // 63 x 4 = 252 blocks
    condlane_fused<<<grid, 512, 98304, stream>>>(x, params, out, num_ins);
}